// Round 1
// baseline (5403.793 us; speedup 1.0000x reference)
//
#include <hip/hip_runtime.h>
#include <hip/hip_cooperative_groups.h>
#include <math.h>

namespace cg = cooperative_groups;

#define SS   96            // S
#define TM   96            // TM1
#define BB   8             // B
#define VV   32000         // V
#define EE   256           // E
#define HH   512           // H
#define NTOK (SS + TM)     // 192
#define G4   (4 * HH)      // 2048
#define NEGF (-1e30f)

// ---- workspace layout (float offsets) ----
#define XIH_OFF   ((size_t)0)
#define XIH_SZ    ((size_t)NTOK * BB * G4)       // 3,145,728 f
#define HALL_OFF  (XIH_OFF + XIH_SZ)
#define HALL_SZ   ((size_t)NTOK * BB * HH)       // 786,432 f
#define Q_OFF     (HALL_OFF + HALL_SZ)
#define Q_SZ      ((size_t)TM * BB * HH)         // 393,216 f
#define PPTR_OFF  (Q_OFF + Q_SZ)
#define ASENT_OFF (PPTR_OFF + (size_t)(TM * BB))
#define SSUM_OFF  (ASENT_OFF + (size_t)(TM * BB))
#define LSTAR_OFF (SSUM_OFF + (size_t)(TM * BB))

__device__ __forceinline__ float sigf(float x) { return 1.f / (1.f + __expf(-x)); }

// ============ Kernel 1: Xih[tok][row] = emb_eff[idx[tok]] . W_ih[row] + b_ih[row]+b_hh[row]
// grid (NTOK*BB/16, G4/256) = (96,8), block 256. Each block: 16 tokens x 256 rows.
__global__ void __launch_bounds__(256) k_xih(const int* __restrict__ src,
                                             const int* __restrict__ tgt,
                                             const float* __restrict__ emb,
                                             const float* __restrict__ Wih,
                                             const float* __restrict__ bih,
                                             const float* __restrict__ bhh,
                                             float* __restrict__ xih) {
    __shared__ float xs[16][EE];   // 16 KB
    const int tok0 = blockIdx.x * 16;
    const int row0 = blockIdx.y * 256;
    const int tid  = threadIdx.x;

    for (int e = tid; e < 16 * EE; e += 256) {
        int tk = e >> 8;          // EE == 256
        int k  = e & 255;
        int tau = tok0 + tk;
        int idx = (tau < SS * BB) ? src[tau] : tgt[tau - SS * BB];
        xs[tk][k] = (idx == 0) ? 0.f : emb[(size_t)idx * EE + k];   // PAD row zeroed
    }
    __syncthreads();

    const int row = row0 + tid;
    const float bias = bih[row] + bhh[row];
    float acc[16];
#pragma unroll
    for (int r = 0; r < 16; ++r) acc[r] = bias;

    const float4* w4 = (const float4*)(Wih + (size_t)row * EE);
    for (int k4 = 0; k4 < EE / 4; ++k4) {
        float4 w = w4[k4];
#pragma unroll
        for (int r = 0; r < 16; ++r) {
            float4 x = *((const float4*)&xs[r][k4 * 4]);   // broadcast across lanes
            acc[r] += w.x * x.x + w.y * x.y + w.z * x.z + w.w * x.w;
        }
    }
#pragma unroll
    for (int r = 0; r < 16; ++r)
        xih[(size_t)(tok0 + r) * G4 + row] = acc[r];
}

// ============ Kernel 2: cooperative LSTM scan, 192 steps ============
// 64 blocks x 256 thr. gid -> b=gid&7, gate=(gid>>3)&3, i=gid>>5. One grid.sync per step.
__global__ void __launch_bounds__(256) k_lstm(const float* __restrict__ xih,
                                              const float* __restrict__ Whh,
                                              float* __restrict__ hall) {
    cg::grid_group grid = cg::this_grid();
    __shared__ float hb[8 * 516];          // padded: (b*516+k)%32 banks spread

    const int tid  = threadIdx.x;
    const int gid  = blockIdx.x * 256 + tid;
    const int b    = gid & 7;
    const int gate = (gid >> 3) & 3;       // 0=i 1=f 2=g 3=o
    const int i    = gid >> 5;
    const int row  = gate * HH + i;
    const float4* w4 = (const float4*)(Whh + (size_t)row * HH);

    float c = 0.f;

    for (int t = 0; t < NTOK; ++t) {
        if (t > 0) {
            const float* hprev = hall + (size_t)(t - 1) * (BB * HH);
            for (int e = tid; e < BB * HH; e += 256)
                hb[(e >> 9) * 516 + (e & 511)] = hprev[e];
        }
        __syncthreads();

        float acc = xih[(size_t)(t * BB + b) * G4 + row];
        if (t > 0) {
            const float4* h4 = (const float4*)(hb + b * 516);
#pragma unroll 8
            for (int k4 = 0; k4 < HH / 4; ++k4) {
                float4 w = w4[k4];
                float4 h = h4[k4];
                acc += w.x * h.x + w.y * h.y + w.z * h.z + w.w * h.w;
            }
        }
        // gather gates: gate-0 lane l0=(i&1)*32+b ; f at +8, g at +16, o at +24
        float gf = __shfl_down(acc, 8, 64);
        float gg = __shfl_down(acc, 16, 64);
        float go = __shfl_down(acc, 24, 64);
        if (gate == 0) {
            float is = sigf(acc);
            float fs = sigf(gf);
            float gv = tanhf(gg);
            float os = sigf(go);
            c = fs * c + is * gv;
            float h = os * tanhf(c);
            hall[(size_t)(t * BB + b) * HH + i] = h;
        }
        __threadfence();
        grid.sync();
    }
}

// ============ Kernel 3: Q = tanh(Hdec @ W_att^T). grid TM, block 256 ============
__global__ void __launch_bounds__(256) k_q(const float* __restrict__ hall,
                                           const float* __restrict__ Watt,
                                           float* __restrict__ q) {
    __shared__ float hb[8 * 516];
    const int t = blockIdx.x, tid = threadIdx.x;
    const float* hdec = hall + (size_t)(SS + t) * (BB * HH);
    for (int e = tid; e < BB * HH; e += 256)
        hb[(e >> 9) * 516 + (e & 511)] = hdec[e];
    __syncthreads();

    for (int oi = tid; oi < BB * HH; oi += 256) {
        int b = oi & 7, ii = oi >> 3;
        const float4* w4 = (const float4*)(Watt + (size_t)ii * HH);
        const float4* h4 = (const float4*)(hb + b * 516);
        float acc = 0.f;
        for (int k4 = 0; k4 < HH / 4; ++k4) {
            float4 w = w4[k4], h = h4[k4];
            acc += w.x * h.x + w.y * h.y + w.z * h.z + w.w * h.w;
        }
        q[(size_t)(t * BB + b) * HH + ii] = tanhf(acc);
    }
}

// ============ Kernel 4: attention scores + softmax + pointer gather ============
// grid (TM, BB), block 256. j = tid: 0..191 -> H_all rows, 192 -> sent.
__global__ void __launch_bounds__(256) k_att(const float* __restrict__ hall,
                                             const float* __restrict__ q,
                                             const float* __restrict__ sent,
                                             const int* __restrict__ src,
                                             const int* __restrict__ tgt,
                                             float* __restrict__ pptr,
                                             float* __restrict__ asent) {
    __shared__ float qs[HH];
    __shared__ float av[256];
    __shared__ float red[256];
    const int t = blockIdx.x, b = blockIdx.y, tid = threadIdx.x;

    for (int e = tid; e < HH; e += 256) qs[e] = q[(size_t)(t * BB + b) * HH + e];
    __syncthreads();

    const int j = tid;
    float acc = NEGF;
    if (j < SS + TM + 1) {
        bool valid = (j < SS + t + 1) || (j == SS + TM);
        if (valid) {
            const float* vptr = (j < SS + TM) ? (hall + (size_t)(j * BB + b) * HH) : sent;
            const float4* v4 = (const float4*)vptr;
            const float4* q4 = (const float4*)qs;
            float a = 0.f;
            for (int k4 = 0; k4 < HH / 4; ++k4) {
                float4 v = v4[k4], qq = q4[k4];
                a += v.x * qq.x + v.y * qq.y + v.z * qq.z + v.w * qq.w;
            }
            acc = a;
        }
    }
    // block max
    red[tid] = acc;
    __syncthreads();
    for (int s2 = 128; s2 > 0; s2 >>= 1) {
        if (tid < s2) red[tid] = fmaxf(red[tid], red[tid + s2]);
        __syncthreads();
    }
    float m = red[0];
    __syncthreads();
    float e = __expf(acc - m);           // NEG -> 0 (also covers tid>=193)
    red[tid] = e;
    __syncthreads();
    for (int s2 = 128; s2 > 0; s2 >>= 1) {
        if (tid < s2) red[tid] += red[tid + s2];
        __syncthreads();
    }
    float denom = red[0];
    __syncthreads();
    float a = e / denom;
    av[tid] = a;
    __syncthreads();

    const int vs = tgt[(t + 1) * BB + b];
    float contrib = 0.f;
    if (j < SS) {
        if (src[j * BB + b] == vs) contrib += av[j];        // a_src
        if (tgt[j * BB + b] == vs) contrib += av[SS + j];   // a_tgt (rows 0..95 of tgt)
    }
    red[tid] = contrib;
    __syncthreads();
    for (int s2 = 128; s2 > 0; s2 >>= 1) {
        if (tid < s2) red[tid] += red[tid + s2];
        __syncthreads();
    }
    if (tid == 0) {
        pptr[t * BB + b]  = red[0];
        asent[t * BB + b] = av[SS + TM];
    }
}

// ============ Kernel 5: vocab softmax stats: ssum[row]=sum_v exp(logit), lstar[row]=logit[v*] ======
// grid (63, 6), block 256. Thread owns cols v0=bx*512+tid*2, v0+1. Row-group by = 128 rows, 4 chunks of 32.
__global__ void __launch_bounds__(256) k_vocab(const float* __restrict__ hall,
                                               const float* __restrict__ Wread,
                                               const int* __restrict__ tgt,
                                               float* __restrict__ ssum,
                                               float* __restrict__ lstar) {
    __shared__ float hs[32 * HH];   // 64 KB, broadcast reads -> no padding needed
    const int tid = threadIdx.x;
    const int v0 = blockIdx.x * 512 + tid * 2;
    const int v1 = v0 + 1;
    const bool g0 = v0 < VV, g1 = v1 < VV;
    const float4* w40 = (const float4*)(Wread + (size_t)(g0 ? v0 : 0) * HH);
    const float4* w41 = (const float4*)(Wread + (size_t)(g1 ? v1 : 0) * HH);
    const int rbase0 = blockIdx.y * 128;

    for (int ch = 0; ch < 4; ++ch) {
        const int rbase = rbase0 + ch * 32;
        // stage 32 Hdec rows (contiguous region of hall)
        const float4* sp4 = (const float4*)(hall + ((size_t)SS * BB + rbase) * HH);
        float4* hs4 = (float4*)hs;
        for (int e = tid; e < 32 * HH / 4; e += 256) hs4[e] = sp4[e];
        __syncthreads();

        float acc0[32], acc1[32];
#pragma unroll
        for (int r = 0; r < 32; ++r) { acc0[r] = 0.f; acc1[r] = 0.f; }

        for (int k4 = 0; k4 < HH / 4; ++k4) {
            float4 w0 = w40[k4];
            float4 w1 = w41[k4];
#pragma unroll
            for (int r = 0; r < 32; ++r) {
                float4 h = *((const float4*)(hs + r * HH + k4 * 4));  // broadcast
                acc0[r] += w0.x * h.x + w0.y * h.y + w0.z * h.z + w0.w * h.w;
                acc1[r] += w1.x * h.x + w1.y * h.y + w1.z * h.z + w1.w * h.w;
            }
        }

#pragma unroll
        for (int r = 0; r < 32; ++r) {
            const int row = rbase + r;
            float val = 0.f;
            if (g0) val += __expf(acc0[r]);
            if (g1) val += __expf(acc1[r]);
#pragma unroll
            for (int d = 32; d > 0; d >>= 1) val += __shfl_xor(val, d, 64);
            if ((tid & 63) == 0) atomicAdd(&ssum[row], val);
            const int vs = tgt[row + BB];   // tgt[(t+1)*B+b] == tgt[row+8]
            if (g0 && v0 == vs) lstar[row] = acc0[r];
            else if (g1 && v1 == vs) lstar[row] = acc1[r];
        }
        __syncthreads();   // hs reused next chunk
    }
}

// ============ Kernel 6: gold log-likelihoods + per-batch sums. 1 block x 768 thr ============
__global__ void __launch_bounds__(768) k_final(const float* __restrict__ pptr,
                                               const float* __restrict__ asent,
                                               const float* __restrict__ ssum,
                                               const float* __restrict__ lstar,
                                               const int* __restrict__ tgt,
                                               float* __restrict__ out) {
    __shared__ float g[TM * BB], gp[TM * BB];
    const int tid = threadIdx.x;          // = t*8+b
    const int vs = tgt[tid + BB];
    const float pv = __expf(lstar[tid]) / ssum[tid];
    const float ps = pptr[tid];
    const float as = asent[tid];
    if (vs != 0) {
        g[tid]  = logf(ps + pv * as);
        gp[tid] = logf(ps + as);
    } else {
        g[tid] = 0.f; gp[tid] = 0.f;
    }
    __syncthreads();
    if (tid < BB) {
        float s1 = 0.f, s2 = 0.f;
        for (int t = 0; t < TM; ++t) { s1 += g[t * BB + tid]; s2 += gp[t * BB + tid]; }
        out[tid] = s1;
        out[BB + tid] = s2;
    }
}

extern "C" void kernel_launch(void* const* d_in, const int* in_sizes, int n_in,
                              void* d_out, int out_size, void* d_ws, size_t ws_size,
                              hipStream_t stream) {
    (void)in_sizes; (void)n_in; (void)out_size; (void)ws_size;
    const int*   src   = (const int*)d_in[0];
    const int*   tgt   = (const int*)d_in[1];
    const float* emb   = (const float*)d_in[2];
    const float* Wih   = (const float*)d_in[3];
    const float* Whh   = (const float*)d_in[4];
    const float* bih   = (const float*)d_in[5];
    const float* bhh   = (const float*)d_in[6];
    const float* Watt  = (const float*)d_in[7];
    const float* sent  = (const float*)d_in[8];
    const float* Wread = (const float*)d_in[9];
    float* ws  = (float*)d_ws;
    float* out = (float*)d_out;

    // zero the exp-sum accumulators (only buffer needing init)
    hipMemsetAsync((void*)(ws + SSUM_OFF), 0, TM * BB * sizeof(float), stream);

    k_xih<<<dim3(NTOK * BB / 16, G4 / 256), 256, 0, stream>>>(
        src, tgt, emb, Wih, bih, bhh, ws + XIH_OFF);

    {
        const float* xih = ws + XIH_OFF;
        const float* whh = Whh;
        float* hall = ws + HALL_OFF;
        void* args[] = { (void*)&xih, (void*)&whh, (void*)&hall };
        hipLaunchCooperativeKernel((void*)k_lstm, dim3(64), dim3(256), args, 0, stream);
    }

    k_q<<<dim3(TM), 256, 0, stream>>>(ws + HALL_OFF, Watt, ws + Q_OFF);

    k_att<<<dim3(TM, BB), 256, 0, stream>>>(ws + HALL_OFF, ws + Q_OFF, sent,
                                            src, tgt, ws + PPTR_OFF, ws + ASENT_OFF);

    k_vocab<<<dim3(63, 6), 256, 0, stream>>>(ws + HALL_OFF, Wread, tgt,
                                             ws + SSUM_OFF, ws + LSTAR_OFF);

    k_final<<<dim3(1), dim3(TM * BB), 0, stream>>>(ws + PPTR_OFF, ws + ASENT_OFF,
                                                   ws + SSUM_OFF, ws + LSTAR_OFF,
                                                   tgt, out);
}

// Round 2
// 2328.214 us; speedup vs baseline: 2.3210x; 2.3210x over previous
//
#include <hip/hip_runtime.h>
#include <hip/hip_cooperative_groups.h>
#include <math.h>

namespace cg = cooperative_groups;

#define SS   96            // S
#define TM   96            // TM1
#define BB   8             // B
#define VV   32000         // V
#define EE   256           // E
#define HH   512           // H
#define NTOK (SS + TM)     // 192
#define G4   (4 * HH)      // 2048
#define NEGF (-1e30f)
#define NBLK 64            // k_lstm grid

// ---- workspace layout (float offsets) ----
#define XIH_OFF   ((size_t)0)
#define XIH_SZ    ((size_t)NTOK * BB * G4)       // 3,145,728 f
#define HALL_OFF  (XIH_OFF + XIH_SZ)
#define HALL_SZ   ((size_t)NTOK * BB * HH)       // 786,432 f
#define Q_OFF     (HALL_OFF + HALL_SZ)
#define Q_SZ      ((size_t)TM * BB * HH)         // 393,216 f
#define PPTR_OFF  (Q_OFF + Q_SZ)
#define ASENT_OFF (PPTR_OFF + (size_t)(TM * BB))
#define SSUM_OFF  (ASENT_OFF + (size_t)(TM * BB))
#define LSTAR_OFF (SSUM_OFF + (size_t)(TM * BB))
#define BAR_OFF   (LSTAR_OFF + (size_t)(TM * BB))   // [0]=cnt, [32]=gen (separate lines)

__device__ __forceinline__ float sigf(float x) { return 1.f / (1.f + __expf(-x)); }

// ============ Kernel 1: Xih[tok][row] = emb_eff[idx[tok]] . W_ih[row] + b_ih[row]+b_hh[row]
__global__ void __launch_bounds__(256) k_xih(const int* __restrict__ src,
                                             const int* __restrict__ tgt,
                                             const float* __restrict__ emb,
                                             const float* __restrict__ Wih,
                                             const float* __restrict__ bih,
                                             const float* __restrict__ bhh,
                                             float* __restrict__ xih) {
    __shared__ float xs[16][EE];   // 16 KB
    const int tok0 = blockIdx.x * 16;
    const int row0 = blockIdx.y * 256;
    const int tid  = threadIdx.x;

    for (int e = tid; e < 16 * EE; e += 256) {
        int tk = e >> 8;          // EE == 256
        int k  = e & 255;
        int tau = tok0 + tk;
        int idx = (tau < SS * BB) ? src[tau] : tgt[tau - SS * BB];
        xs[tk][k] = (idx == 0) ? 0.f : emb[(size_t)idx * EE + k];   // PAD row zeroed
    }
    __syncthreads();

    const int row = row0 + tid;
    const float bias = bih[row] + bhh[row];
    float acc[16];
#pragma unroll
    for (int r = 0; r < 16; ++r) acc[r] = bias;

    const float4* w4 = (const float4*)(Wih + (size_t)row * EE);
    for (int k4 = 0; k4 < EE / 4; ++k4) {
        float4 w = w4[k4];
#pragma unroll
        for (int r = 0; r < 16; ++r) {
            float4 x = *((const float4*)&xs[r][k4 * 4]);   // broadcast across lanes
            acc[r] += w.x * x.x + w.y * x.y + w.z * x.z + w.w * x.w;
        }
    }
#pragma unroll
    for (int r = 0; r < 16; ++r)
        xih[(size_t)(tok0 + r) * G4 + row] = acc[r];
}

// ============ Kernel 2: LSTM scan, 192 steps, custom L3-coherent barrier ============
// 64 blocks x 256 thr. gid -> b=gid&7, gate=(gid>>3)&3, i=gid>>5.
// h exchanged via sc0/sc1 (agent-scope) stores/loads -> coherent at L3, no L2 wb/inv.
__global__ void __launch_bounds__(256) k_lstm(const float* __restrict__ xih,
                                              const float* __restrict__ Whh,
                                              float* __restrict__ hall,
                                              unsigned* __restrict__ bar) {
    __shared__ float hb[8 * 516];          // padded: banks spread

    const int tid  = threadIdx.x;
    const int gid  = blockIdx.x * 256 + tid;
    const int b    = gid & 7;
    const int gate = (gid >> 3) & 3;       // 0=i 1=f 2=g 3=o
    const int i    = gid >> 5;
    const int row  = gate * HH + i;
    const float4* w4 = (const float4*)(Whh + (size_t)row * HH);
    unsigned* bar_cnt = bar;
    unsigned* bar_gen = bar + 32;

    float c = 0.f;
    float xnext = xih[(size_t)(0 * BB + b) * G4 + row];

    for (int t = 0; t < NTOK; ++t) {
        float acc = xnext;
        if (t > 0) {
            // stage h_{t-1}: agent-scope loads -> fetch fresh from L3 coherent point
            const float* hprev = hall + (size_t)(t - 1) * (BB * HH);
            float tmp[16];
#pragma unroll
            for (int u = 0; u < 16; ++u)
                tmp[u] = __hip_atomic_load(hprev + tid + u * 256,
                                           __ATOMIC_RELAXED, __HIP_MEMORY_SCOPE_AGENT);
#pragma unroll
            for (int u = 0; u < 16; ++u) {
                int e = tid + u * 256;
                hb[(e >> 9) * 516 + (e & 511)] = tmp[u];
            }
        }
        __syncthreads();

        if (t > 0) {
            const float4* h4 = (const float4*)(hb + b * 516);
#pragma unroll 8
            for (int k4 = 0; k4 < HH / 4; ++k4) {
                float4 w = w4[k4];
                float4 h = h4[k4];
                acc += w.x * h.x + w.y * h.y + w.z * h.z + w.w * h.w;
            }
        }
        // gather gates: gate-0 lane has i,f,g,o at lane offsets 0,8,16,24
        float gf = __shfl_down(acc, 8, 64);
        float gg = __shfl_down(acc, 16, 64);
        float go = __shfl_down(acc, 24, 64);
        if (gate == 0) {
            float is = sigf(acc);
            float fs = sigf(gf);
            float gv = tanhf(gg);
            float os = sigf(go);
            c = fs * c + is * gv;
            float h = os * tanhf(c);
            // write-through to coherent point (L3) -- visible device-wide, no L2 flush
            __hip_atomic_store(&hall[(size_t)(t * BB + b) * HH + i], h,
                               __ATOMIC_RELAXED, __HIP_MEMORY_SCOPE_AGENT);
        }

        if (t < NTOK - 1) {
            // prefetch next step's xih before the barrier (hides L2/L3 latency)
            xnext = xih[(size_t)((t + 1) * BB + b) * G4 + row];

            // grid barrier: monotone generation, one atomic per block.
            // compiler emits s_waitcnt vmcnt(0) before s_barrier -> h stores drained.
            __syncthreads();
            if (tid == 0) {
                unsigned prev = __hip_atomic_fetch_add(bar_cnt, 1u,
                                    __ATOMIC_RELEASE, __HIP_MEMORY_SCOPE_AGENT);
                if (prev == NBLK - 1) {
                    __hip_atomic_store(bar_cnt, 0u,
                                       __ATOMIC_RELAXED, __HIP_MEMORY_SCOPE_AGENT);
                    __hip_atomic_store(bar_gen, (unsigned)(t + 1),
                                       __ATOMIC_RELEASE, __HIP_MEMORY_SCOPE_AGENT);
                } else {
                    while (__hip_atomic_load(bar_gen, __ATOMIC_RELAXED,
                                             __HIP_MEMORY_SCOPE_AGENT) < (unsigned)(t + 1)) {}
                }
            }
            __syncthreads();
        }
    }
}

// ============ Kernel 3: Q = tanh(Hdec @ W_att^T). grid TM, block 256 ============
__global__ void __launch_bounds__(256) k_q(const float* __restrict__ hall,
                                           const float* __restrict__ Watt,
                                           float* __restrict__ q) {
    __shared__ float hb[8 * 516];
    const int t = blockIdx.x, tid = threadIdx.x;
    const float* hdec = hall + (size_t)(SS + t) * (BB * HH);
    for (int e = tid; e < BB * HH; e += 256)
        hb[(e >> 9) * 516 + (e & 511)] = hdec[e];
    __syncthreads();

    for (int oi = tid; oi < BB * HH; oi += 256) {
        int b = oi & 7, ii = oi >> 3;
        const float4* w4 = (const float4*)(Watt + (size_t)ii * HH);
        const float4* h4 = (const float4*)(hb + b * 516);
        float acc = 0.f;
        for (int k4 = 0; k4 < HH / 4; ++k4) {
            float4 w = w4[k4], h = h4[k4];
            acc += w.x * h.x + w.y * h.y + w.z * h.z + w.w * h.w;
        }
        q[(size_t)(t * BB + b) * HH + ii] = tanhf(acc);
    }
}

// ============ Kernel 4: attention scores + softmax + pointer gather ============
__global__ void __launch_bounds__(256) k_att(const float* __restrict__ hall,
                                             const float* __restrict__ q,
                                             const float* __restrict__ sent,
                                             const int* __restrict__ src,
                                             const int* __restrict__ tgt,
                                             float* __restrict__ pptr,
                                             float* __restrict__ asent) {
    __shared__ float qs[HH];
    __shared__ float av[256];
    __shared__ float red[256];
    const int t = blockIdx.x, b = blockIdx.y, tid = threadIdx.x;

    for (int e = tid; e < HH; e += 256) qs[e] = q[(size_t)(t * BB + b) * HH + e];
    __syncthreads();

    const int j = tid;
    float acc = NEGF;
    if (j < SS + TM + 1) {
        bool valid = (j < SS + t + 1) || (j == SS + TM);
        if (valid) {
            const float* vptr = (j < SS + TM) ? (hall + (size_t)(j * BB + b) * HH) : sent;
            const float4* v4 = (const float4*)vptr;
            const float4* q4 = (const float4*)qs;
            float a = 0.f;
            for (int k4 = 0; k4 < HH / 4; ++k4) {
                float4 v = v4[k4], qq = q4[k4];
                a += v.x * qq.x + v.y * qq.y + v.z * qq.z + v.w * qq.w;
            }
            acc = a;
        }
    }
    red[tid] = acc;
    __syncthreads();
    for (int s2 = 128; s2 > 0; s2 >>= 1) {
        if (tid < s2) red[tid] = fmaxf(red[tid], red[tid + s2]);
        __syncthreads();
    }
    float m = red[0];
    __syncthreads();
    float e = __expf(acc - m);
    red[tid] = e;
    __syncthreads();
    for (int s2 = 128; s2 > 0; s2 >>= 1) {
        if (tid < s2) red[tid] += red[tid + s2];
        __syncthreads();
    }
    float denom = red[0];
    __syncthreads();
    float a = e / denom;
    av[tid] = a;
    __syncthreads();

    const int vs = tgt[(t + 1) * BB + b];
    float contrib = 0.f;
    if (j < SS) {
        if (src[j * BB + b] == vs) contrib += av[j];        // a_src
        if (tgt[j * BB + b] == vs) contrib += av[SS + j];   // a_tgt
    }
    red[tid] = contrib;
    __syncthreads();
    for (int s2 = 128; s2 > 0; s2 >>= 1) {
        if (tid < s2) red[tid] += red[tid + s2];
        __syncthreads();
    }
    if (tid == 0) {
        pptr[t * BB + b]  = red[0];
        asent[t * BB + b] = av[SS + TM];
    }
}

// ============ Kernel 5: vocab softmax stats ============
__global__ void __launch_bounds__(256) k_vocab(const float* __restrict__ hall,
                                               const float* __restrict__ Wread,
                                               const int* __restrict__ tgt,
                                               float* __restrict__ ssum,
                                               float* __restrict__ lstar) {
    __shared__ float hs[32 * HH];   // 64 KB
    const int tid = threadIdx.x;
    const int v0 = blockIdx.x * 512 + tid * 2;
    const int v1 = v0 + 1;
    const bool g0 = v0 < VV, g1 = v1 < VV;
    const float4* w40 = (const float4*)(Wread + (size_t)(g0 ? v0 : 0) * HH);
    const float4* w41 = (const float4*)(Wread + (size_t)(g1 ? v1 : 0) * HH);
    const int rbase0 = blockIdx.y * 128;

    for (int ch = 0; ch < 4; ++ch) {
        const int rbase = rbase0 + ch * 32;
        const float4* sp4 = (const float4*)(hall + ((size_t)SS * BB + rbase) * HH);
        float4* hs4 = (float4*)hs;
        for (int e = tid; e < 32 * HH / 4; e += 256) hs4[e] = sp4[e];
        __syncthreads();

        float acc0[32], acc1[32];
#pragma unroll
        for (int r = 0; r < 32; ++r) { acc0[r] = 0.f; acc1[r] = 0.f; }

        for (int k4 = 0; k4 < HH / 4; ++k4) {
            float4 w0 = w40[k4];
            float4 w1 = w41[k4];
#pragma unroll
            for (int r = 0; r < 32; ++r) {
                float4 h = *((const float4*)(hs + r * HH + k4 * 4));
                acc0[r] += w0.x * h.x + w0.y * h.y + w0.z * h.z + w0.w * h.w;
                acc1[r] += w1.x * h.x + w1.y * h.y + w1.z * h.z + w1.w * h.w;
            }
        }

#pragma unroll
        for (int r = 0; r < 32; ++r) {
            const int row = rbase + r;
            float val = 0.f;
            if (g0) val += __expf(acc0[r]);
            if (g1) val += __expf(acc1[r]);
#pragma unroll
            for (int d = 32; d > 0; d >>= 1) val += __shfl_xor(val, d, 64);
            if ((tid & 63) == 0) atomicAdd(&ssum[row], val);
            const int vs = tgt[row + BB];
            if (g0 && v0 == vs) lstar[row] = acc0[r];
            else if (g1 && v1 == vs) lstar[row] = acc1[r];
        }
        __syncthreads();
    }
}

// ============ Kernel 6: gold log-likelihoods + per-batch sums ============
__global__ void __launch_bounds__(768) k_final(const float* __restrict__ pptr,
                                               const float* __restrict__ asent,
                                               const float* __restrict__ ssum,
                                               const float* __restrict__ lstar,
                                               const int* __restrict__ tgt,
                                               float* __restrict__ out) {
    __shared__ float g[TM * BB], gp[TM * BB];
    const int tid = threadIdx.x;          // = t*8+b
    const int vs = tgt[tid + BB];
    const float pv = __expf(lstar[tid]) / ssum[tid];
    const float ps = pptr[tid];
    const float as = asent[tid];
    if (vs != 0) {
        g[tid]  = logf(ps + pv * as);
        gp[tid] = logf(ps + as);
    } else {
        g[tid] = 0.f; gp[tid] = 0.f;
    }
    __syncthreads();
    if (tid < BB) {
        float s1 = 0.f, s2 = 0.f;
        for (int t = 0; t < TM; ++t) { s1 += g[t * BB + tid]; s2 += gp[t * BB + tid]; }
        out[tid] = s1;
        out[BB + tid] = s2;
    }
}

extern "C" void kernel_launch(void* const* d_in, const int* in_sizes, int n_in,
                              void* d_out, int out_size, void* d_ws, size_t ws_size,
                              hipStream_t stream) {
    (void)in_sizes; (void)n_in; (void)out_size; (void)ws_size;
    const int*   src   = (const int*)d_in[0];
    const int*   tgt   = (const int*)d_in[1];
    const float* emb   = (const float*)d_in[2];
    const float* Wih   = (const float*)d_in[3];
    const float* Whh   = (const float*)d_in[4];
    const float* bih   = (const float*)d_in[5];
    const float* bhh   = (const float*)d_in[6];
    const float* Watt  = (const float*)d_in[7];
    const float* sent  = (const float*)d_in[8];
    const float* Wread = (const float*)d_in[9];
    float* ws  = (float*)d_ws;
    float* out = (float*)d_out;

    // zero exp-sum accumulators + barrier state
    hipMemsetAsync((void*)(ws + SSUM_OFF), 0, TM * BB * sizeof(float), stream);
    hipMemsetAsync((void*)(ws + BAR_OFF), 0, 64 * sizeof(unsigned), stream);

    k_xih<<<dim3(NTOK * BB / 16, G4 / 256), 256, 0, stream>>>(
        src, tgt, emb, Wih, bih, bhh, ws + XIH_OFF);

    {
        const float* xih = ws + XIH_OFF;
        const float* whh = Whh;
        float* hall = ws + HALL_OFF;
        unsigned* bar = (unsigned*)(ws + BAR_OFF);
        void* args[] = { (void*)&xih, (void*)&whh, (void*)&hall, (void*)&bar };
        hipLaunchCooperativeKernel((void*)k_lstm, dim3(NBLK), dim3(256), args, 0, stream);
    }

    k_q<<<dim3(TM), 256, 0, stream>>>(ws + HALL_OFF, Watt, ws + Q_OFF);

    k_att<<<dim3(TM, BB), 256, 0, stream>>>(ws + HALL_OFF, ws + Q_OFF, sent,
                                            src, tgt, ws + PPTR_OFF, ws + ASENT_OFF);

    k_vocab<<<dim3(63, 6), 256, 0, stream>>>(ws + HALL_OFF, Wread, tgt,
                                             ws + SSUM_OFF, ws + LSTAR_OFF);

    k_final<<<dim3(1), dim3(TM * BB), 0, stream>>>(ws + PPTR_OFF, ws + ASENT_OFF,
                                                   ws + SSUM_OFF, ws + LSTAR_OFF,
                                                   tgt, out);
}

// Round 3
// 1519.825 us; speedup vs baseline: 3.5555x; 1.5319x over previous
//
#include <hip/hip_runtime.h>
#include <hip/hip_cooperative_groups.h>
#include <math.h>

#define SS   96            // S
#define TM   96            // TM1
#define BB   8             // B
#define VV   32000         // V
#define EE   256           // E
#define HH   512           // H
#define NTOK (SS + TM)     // 192
#define G4   (4 * HH)      // 2048
#define NEGF (-1e30f)
#define NBLK 64            // k_lstm grid (== poll wave width!)

typedef __attribute__((ext_vector_type(8))) short short8;
typedef __attribute__((ext_vector_type(4))) float f32x4;

// ---- workspace layout (float offsets) ----
#define XIH_OFF   ((size_t)0)
#define XIH_SZ    ((size_t)NTOK * BB * G4)       // 3,145,728 f
#define HALL_OFF  (XIH_OFF + XIH_SZ)
#define HALL_SZ   ((size_t)NTOK * BB * HH)       // 786,432 f
#define Q_OFF     (HALL_OFF + HALL_SZ)
#define Q_SZ      ((size_t)TM * BB * HH)         // 393,216 f
#define PPTR_OFF  (Q_OFF + Q_SZ)
#define ASENT_OFF (PPTR_OFF + (size_t)(TM * BB))
#define SSUM_OFF  (ASENT_OFF + (size_t)(TM * BB))
#define LSTAR_OFF (SSUM_OFF + (size_t)(TM * BB))
#define BAR_OFF   (LSTAR_OFF + (size_t)(TM * BB))   // 64 slots x 16 uints (64B spacing)
#define ABF_OFF   (BAR_OFF + (size_t)1024)
#define ABF_SZF   ((size_t)(768 * HH) / 2)          // 196,608 f (768x512 bf16)
#define WBF_OFF   (ABF_OFF + ABF_SZF)
#define WBF_SZF   ((size_t)VV * HH / 2)             // 8,192,000 f (32000x512 bf16)
#define NEED_F    (WBF_OFF + WBF_SZF)

__device__ __forceinline__ float sigf(float x) { return 1.f / (1.f + __expf(-x)); }

// ============ Kernel 1: Xih[tok][row] = emb_eff[idx[tok]] . W_ih[row] + b_ih[row]+b_hh[row]
__global__ void __launch_bounds__(256) k_xih(const int* __restrict__ src,
                                             const int* __restrict__ tgt,
                                             const float* __restrict__ emb,
                                             const float* __restrict__ Wih,
                                             const float* __restrict__ bih,
                                             const float* __restrict__ bhh,
                                             float* __restrict__ xih) {
    __shared__ float xs[16][EE];   // 16 KB
    const int tok0 = blockIdx.x * 16;
    const int row0 = blockIdx.y * 256;
    const int tid  = threadIdx.x;

    for (int e = tid; e < 16 * EE; e += 256) {
        int tk = e >> 8;          // EE == 256
        int k  = e & 255;
        int tau = tok0 + tk;
        int idx = (tau < SS * BB) ? src[tau] : tgt[tau - SS * BB];
        xs[tk][k] = (idx == 0) ? 0.f : emb[(size_t)idx * EE + k];   // PAD row zeroed
    }
    __syncthreads();

    const int row = row0 + tid;
    const float bias = bih[row] + bhh[row];
    float acc[16];
#pragma unroll
    for (int r = 0; r < 16; ++r) acc[r] = bias;

    const float4* w4 = (const float4*)(Wih + (size_t)row * EE);
    for (int k4 = 0; k4 < EE / 4; ++k4) {
        float4 w = w4[k4];
#pragma unroll
        for (int r = 0; r < 16; ++r) {
            float4 x = *((const float4*)&xs[r][k4 * 4]);   // broadcast across lanes
            acc[r] += w.x * x.x + w.y * x.y + w.z * x.z + w.w * x.w;
        }
    }
#pragma unroll
    for (int r = 0; r < 16; ++r)
        xih[(size_t)(tok0 + r) * G4 + row] = acc[r];
}

// ============ Kernel 2: LSTM scan, distributed-slot grid barrier ============
// 64 blocks x 256 thr. gid -> b=gid&7, gate=(gid>>3)&3, i=gid>>5.
// Arrival: one relaxed agent store per block to its own 64B-spaced slot (no RMW).
// Detect: wave0 lanes poll all 64 slots in parallel (monotone generation).
__global__ void __launch_bounds__(256) k_lstm(const float* __restrict__ xih,
                                              const float* __restrict__ Whh,
                                              float* __restrict__ hall,
                                              unsigned* __restrict__ bar) {
    __shared__ float hb[8 * 516];          // padded: banks spread

    const int tid  = threadIdx.x;
    const int gid  = blockIdx.x * 256 + tid;
    const int b    = gid & 7;
    const int gate = (gid >> 3) & 3;       // 0=i 1=f 2=g 3=o
    const int i    = gid >> 5;
    const int row  = gate * HH + i;
    const float4* w4 = (const float4*)(Whh + (size_t)row * HH);

    float c = 0.f;
    float xnext = xih[(size_t)(0 * BB + b) * G4 + row];

    for (int t = 0; t < NTOK; ++t) {
        float acc = xnext;
        if (t > 0) {
            // stage h_{t-1}: agent-scope loads fetch fresh from the coherent point
            const float* hprev = hall + (size_t)(t - 1) * (BB * HH);
            float tmp[16];
#pragma unroll
            for (int u = 0; u < 16; ++u)
                tmp[u] = __hip_atomic_load(hprev + tid + u * 256,
                                           __ATOMIC_RELAXED, __HIP_MEMORY_SCOPE_AGENT);
#pragma unroll
            for (int u = 0; u < 16; ++u) {
                int e = tid + u * 256;
                hb[(e >> 9) * 516 + (e & 511)] = tmp[u];
            }
            __syncthreads();   // staging visible to block

            const float4* h4 = (const float4*)(hb + b * 516);
#pragma unroll 8
            for (int k4 = 0; k4 < HH / 4; ++k4) {
                float4 w = w4[k4];
                float4 h = h4[k4];
                acc += w.x * h.x + w.y * h.y + w.z * h.z + w.w * h.w;
            }
        }
        // gather gates: gate-0 lane has i,f,g,o at lane offsets 0,8,16,24
        float gf = __shfl_down(acc, 8, 64);
        float gg = __shfl_down(acc, 16, 64);
        float go = __shfl_down(acc, 24, 64);
        if (gate == 0) {
            float is = sigf(acc);
            float fs = sigf(gf);
            float gv = tanhf(gg);
            float os = sigf(go);
            c = fs * c + is * gv;
            float h = os * tanhf(c);
            // write-through to coherent point (L3) -- visible device-wide
            __hip_atomic_store(&hall[(size_t)(t * BB + b) * HH + i], h,
                               __ATOMIC_RELAXED, __HIP_MEMORY_SCOPE_AGENT);
        }

        if (t < NTOK - 1) {
            // prefetch next step's xih (in flight during barrier drain)
            xnext = xih[(size_t)((t + 1) * BB + b) * G4 + row];

            __syncthreads();   // drains each wave's h-stores (vmcnt0 before s_barrier)
            const unsigned target = (unsigned)(t + 1);
            if (tid == 0)
                __hip_atomic_store(&bar[(size_t)blockIdx.x * 16], target,
                                   __ATOMIC_RELAXED, __HIP_MEMORY_SCOPE_AGENT);
            if (tid < 64) {
                // lane l polls block l's slot; wave reconverges when all 64 ready
                while (__hip_atomic_load(&bar[(size_t)tid * 16], __ATOMIC_RELAXED,
                                         __HIP_MEMORY_SCOPE_AGENT) < target) {}
            }
            __syncthreads();   // release waves 1..3
        }
    }
}

// ============ Kernel 3: Q = tanh(Hdec @ W_att^T). grid TM, block 256 ============
__global__ void __launch_bounds__(256) k_q(const float* __restrict__ hall,
                                           const float* __restrict__ Watt,
                                           float* __restrict__ q) {
    __shared__ float hb[8 * 516];
    const int t = blockIdx.x, tid = threadIdx.x;
    const float* hdec = hall + (size_t)(SS + t) * (BB * HH);
    for (int e = tid; e < BB * HH; e += 256)
        hb[(e >> 9) * 516 + (e & 511)] = hdec[e];
    __syncthreads();

    for (int oi = tid; oi < BB * HH; oi += 256) {
        int b = oi & 7, ii = oi >> 3;
        const float4* w4 = (const float4*)(Watt + (size_t)ii * HH);
        const float4* h4 = (const float4*)(hb + b * 516);
        float acc = 0.f;
        for (int k4 = 0; k4 < HH / 4; ++k4) {
            float4 w = w4[k4], h = h4[k4];
            acc += w.x * h.x + w.y * h.y + w.z * h.z + w.w * h.w;
        }
        q[(size_t)(t * BB + b) * HH + ii] = tanhf(acc);
    }
}

// ============ Kernel 4: attention scores + softmax + pointer gather ============
__global__ void __launch_bounds__(256) k_att(const float* __restrict__ hall,
                                             const float* __restrict__ q,
                                             const float* __restrict__ sent,
                                             const int* __restrict__ src,
                                             const int* __restrict__ tgt,
                                             float* __restrict__ pptr,
                                             float* __restrict__ asent) {
    __shared__ float qs[HH];
    __shared__ float av[256];
    __shared__ float red[256];
    const int t = blockIdx.x, b = blockIdx.y, tid = threadIdx.x;

    for (int e = tid; e < HH; e += 256) qs[e] = q[(size_t)(t * BB + b) * HH + e];
    __syncthreads();

    const int j = tid;
    float acc = NEGF;
    if (j < SS + TM + 1) {
        bool valid = (j < SS + t + 1) || (j == SS + TM);
        if (valid) {
            const float* vptr = (j < SS + TM) ? (hall + (size_t)(j * BB + b) * HH) : sent;
            const float4* v4 = (const float4*)vptr;
            const float4* q4 = (const float4*)qs;
            float a = 0.f;
            for (int k4 = 0; k4 < HH / 4; ++k4) {
                float4 v = v4[k4], qq = q4[k4];
                a += v.x * qq.x + v.y * qq.y + v.z * qq.z + v.w * qq.w;
            }
            acc = a;
        }
    }
    red[tid] = acc;
    __syncthreads();
    for (int s2 = 128; s2 > 0; s2 >>= 1) {
        if (tid < s2) red[tid] = fmaxf(red[tid], red[tid + s2]);
        __syncthreads();
    }
    float m = red[0];
    __syncthreads();
    float e = __expf(acc - m);
    red[tid] = e;
    __syncthreads();
    for (int s2 = 128; s2 > 0; s2 >>= 1) {
        if (tid < s2) red[tid] += red[tid + s2];
        __syncthreads();
    }
    float denom = red[0];
    __syncthreads();
    float a = e / denom;
    av[tid] = a;
    __syncthreads();

    const int vs = tgt[(t + 1) * BB + b];
    float contrib = 0.f;
    if (j < SS) {
        if (src[j * BB + b] == vs) contrib += av[j];        // a_src
        if (tgt[j * BB + b] == vs) contrib += av[SS + j];   // a_tgt
    }
    red[tid] = contrib;
    __syncthreads();
    for (int s2 = 128; s2 > 0; s2 >>= 1) {
        if (tid < s2) red[tid] += red[tid + s2];
        __syncthreads();
    }
    if (tid == 0) {
        pptr[t * BB + b]  = red[0];
        asent[t * BB + b] = av[SS + TM];
    }
}

// ============ Kernel 5a: f32 -> bf16 conversion (Wread then Hdec) ============
__device__ __forceinline__ unsigned short f2bf(float x) {
    unsigned bits = __float_as_uint(x);
    bits += 0x7FFFu + ((bits >> 16) & 1u);   // RNE
    return (unsigned short)(bits >> 16);
}
__global__ void __launch_bounds__(256) k_cvt(const float* __restrict__ Wread,
                                             const float* __restrict__ hdec,
                                             unsigned short* __restrict__ Wbf,
                                             unsigned short* __restrict__ Abf) {
    const size_t WN = (size_t)VV * HH;          // 16,384,000 (divisible by 8)
    const size_t AN = (size_t)768 * HH;         // 393,216
    size_t base = ((size_t)blockIdx.x * 256 + threadIdx.x) * 8;
    const float* src; unsigned short* dst; size_t off;
    if (base < WN) { src = Wread; dst = Wbf; off = base; }
    else           { src = hdec;  dst = Abf; off = base - WN; if (off >= AN) return; }
    float4 f0 = *(const float4*)(src + off);
    float4 f1 = *(const float4*)(src + off + 4);
    uint4 o;
    o.x = (unsigned)f2bf(f0.x) | ((unsigned)f2bf(f0.y) << 16);
    o.y = (unsigned)f2bf(f0.z) | ((unsigned)f2bf(f0.w) << 16);
    o.z = (unsigned)f2bf(f1.x) | ((unsigned)f2bf(f1.y) << 16);
    o.w = (unsigned)f2bf(f1.z) | ((unsigned)f2bf(f1.w) << 16);
    *(uint4*)(dst + off) = o;
}

// ============ Kernel 5b: vocab softmax stats via bf16 MFMA ============
// grid 500 blocks (64 cols each), block 256 = 4 waves (16 rows each), 12 row passes.
// NT GEMM: A=hdec_bf[row][k], B=Wread_bf[col][k]; frag = 16B contiguous k per lane.
// D layout (m89-verified): col = lane&15, row = 4*(lane>>4)+reg.
__global__ void __launch_bounds__(256) k_vocab_mfma(const unsigned short* __restrict__ Abf,
                                                    const unsigned short* __restrict__ Wbf,
                                                    const int* __restrict__ tgt,
                                                    float* __restrict__ ssum,
                                                    float* __restrict__ lstar) {
    const int tid  = threadIdx.x;
    const int wave = tid >> 6;
    const int lane = tid & 63;
    const int r16  = lane & 15;
    const int kg   = lane >> 4;          // 0..3
    const int n0   = blockIdx.x * 64;

    const unsigned short* b0 = Wbf + (size_t)(n0 +  0 + r16) * HH + kg * 8;
    const unsigned short* b1 = Wbf + (size_t)(n0 + 16 + r16) * HH + kg * 8;
    const unsigned short* b2 = Wbf + (size_t)(n0 + 32 + r16) * HH + kg * 8;
    const unsigned short* b3 = Wbf + (size_t)(n0 + 48 + r16) * HH + kg * 8;

    for (int pass = 0; pass < 12; ++pass) {
        const int row0 = pass * 64 + wave * 16;
        const unsigned short* arow = Abf + (size_t)(row0 + r16) * HH + kg * 8;

        f32x4 acc0 = {0.f,0.f,0.f,0.f}, acc1 = acc0, acc2 = acc0, acc3 = acc0;
#pragma unroll
        for (int ks = 0; ks < 16; ++ks) {
            short8 a = *(const short8*)(arow + ks * 32);
            acc0 = __builtin_amdgcn_mfma_f32_16x16x32_bf16(a, *(const short8*)(b0 + ks * 32), acc0, 0, 0, 0);
            acc1 = __builtin_amdgcn_mfma_f32_16x16x32_bf16(a, *(const short8*)(b1 + ks * 32), acc1, 0, 0, 0);
            acc2 = __builtin_amdgcn_mfma_f32_16x16x32_bf16(a, *(const short8*)(b2 + ks * 32), acc2, 0, 0, 0);
            acc3 = __builtin_amdgcn_mfma_f32_16x16x32_bf16(a, *(const short8*)(b3 + ks * 32), acc3, 0, 0, 0);
        }

        // lane holds rows row0+4*kg+reg, col n0+s*16+r16
#pragma unroll
        for (int reg = 0; reg < 4; ++reg) {
            const int rowg = row0 + 4 * kg + reg;
            const int vs = tgt[BB + rowg];
            int cg;
            cg = n0 +  0 + r16; if (cg == vs) lstar[rowg] = acc0[reg];
            cg = n0 + 16 + r16; if (cg == vs) lstar[rowg] = acc1[reg];
            cg = n0 + 32 + r16; if (cg == vs) lstar[rowg] = acc2[reg];
            cg = n0 + 48 + r16; if (cg == vs) lstar[rowg] = acc3[reg];

            float v = __expf(acc0[reg]) + __expf(acc1[reg]) +
                      __expf(acc2[reg]) + __expf(acc3[reg]);
            v += __shfl_xor(v, 1, 64);
            v += __shfl_xor(v, 2, 64);
            v += __shfl_xor(v, 4, 64);
            v += __shfl_xor(v, 8, 64);
            if (r16 == 0) atomicAdd(&ssum[rowg], v);
        }
    }
}

// ============ Kernel 5-fallback: f32 vocab stats (used if ws too small) ============
__global__ void __launch_bounds__(256) k_vocab_f32(const float* __restrict__ hall,
                                                   const float* __restrict__ Wread,
                                                   const int* __restrict__ tgt,
                                                   float* __restrict__ ssum,
                                                   float* __restrict__ lstar) {
    __shared__ float hs[32 * HH];   // 64 KB
    const int tid = threadIdx.x;
    const int v0 = blockIdx.x * 512 + tid * 2;
    const int v1 = v0 + 1;
    const bool g0 = v0 < VV, g1 = v1 < VV;
    const float4* w40 = (const float4*)(Wread + (size_t)(g0 ? v0 : 0) * HH);
    const float4* w41 = (const float4*)(Wread + (size_t)(g1 ? v1 : 0) * HH);
    const int rbase0 = blockIdx.y * 128;

    for (int ch = 0; ch < 4; ++ch) {
        const int rbase = rbase0 + ch * 32;
        const float4* sp4 = (const float4*)(hall + ((size_t)SS * BB + rbase) * HH);
        float4* hs4 = (float4*)hs;
        for (int e = tid; e < 32 * HH / 4; e += 256) hs4[e] = sp4[e];
        __syncthreads();

        float acc0[32], acc1[32];
#pragma unroll
        for (int r = 0; r < 32; ++r) { acc0[r] = 0.f; acc1[r] = 0.f; }

        for (int k4 = 0; k4 < HH / 4; ++k4) {
            float4 w0 = w40[k4];
            float4 w1 = w41[k4];
#pragma unroll
            for (int r = 0; r < 32; ++r) {
                float4 h = *((const float4*)(hs + r * HH + k4 * 4));
                acc0[r] += w0.x * h.x + w0.y * h.y + w0.z * h.z + w0.w * h.w;
                acc1[r] += w1.x * h.x + w1.y * h.y + w1.z * h.z + w1.w * h.w;
            }
        }

#pragma unroll
        for (int r = 0; r < 32; ++r) {
            const int row = rbase + r;
            float val = 0.f;
            if (g0) val += __expf(acc0[r]);
            if (g1) val += __expf(acc1[r]);
#pragma unroll
            for (int d = 32; d > 0; d >>= 1) val += __shfl_xor(val, d, 64);
            if ((tid & 63) == 0) atomicAdd(&ssum[row], val);
            const int vs = tgt[row + BB];
            if (g0 && v0 == vs) lstar[row] = acc0[r];
            else if (g1 && v1 == vs) lstar[row] = acc1[r];
        }
        __syncthreads();
    }
}

// ============ Kernel 6: gold log-likelihoods + per-batch sums ============
__global__ void __launch_bounds__(768) k_final(const float* __restrict__ pptr,
                                               const float* __restrict__ asent,
                                               const float* __restrict__ ssum,
                                               const float* __restrict__ lstar,
                                               const int* __restrict__ tgt,
                                               float* __restrict__ out) {
    __shared__ float g[TM * BB], gp[TM * BB];
    const int tid = threadIdx.x;          // = t*8+b
    const int vs = tgt[tid + BB];
    const float pv = __expf(lstar[tid]) / ssum[tid];
    const float ps = pptr[tid];
    const float as = asent[tid];
    if (vs != 0) {
        g[tid]  = logf(ps + pv * as);
        gp[tid] = logf(ps + as);
    } else {
        g[tid] = 0.f; gp[tid] = 0.f;
    }
    __syncthreads();
    if (tid < BB) {
        float s1 = 0.f, s2 = 0.f;
        for (int t = 0; t < TM; ++t) { s1 += g[t * BB + tid]; s2 += gp[t * BB + tid]; }
        out[tid] = s1;
        out[BB + tid] = s2;
    }
}

extern "C" void kernel_launch(void* const* d_in, const int* in_sizes, int n_in,
                              void* d_out, int out_size, void* d_ws, size_t ws_size,
                              hipStream_t stream) {
    (void)in_sizes; (void)n_in; (void)out_size;
    const int*   src   = (const int*)d_in[0];
    const int*   tgt   = (const int*)d_in[1];
    const float* emb   = (const float*)d_in[2];
    const float* Wih   = (const float*)d_in[3];
    const float* Whh   = (const float*)d_in[4];
    const float* bih   = (const float*)d_in[5];
    const float* bhh   = (const float*)d_in[6];
    const float* Watt  = (const float*)d_in[7];
    const float* sent  = (const float*)d_in[8];
    const float* Wread = (const float*)d_in[9];
    float* ws  = (float*)d_ws;
    float* out = (float*)d_out;

    const bool use_mfma = ws_size >= NEED_F * sizeof(float);

    // zero SSUM + LSTAR + BAR in one shot (contiguous)
    hipMemsetAsync((void*)(ws + SSUM_OFF), 0,
                   (size_t)(TM * BB * 2 + 1024) * sizeof(float), stream);

    k_xih<<<dim3(NTOK * BB / 16, G4 / 256), 256, 0, stream>>>(
        src, tgt, emb, Wih, bih, bhh, ws + XIH_OFF);

    {
        const float* xih = ws + XIH_OFF;
        const float* whh = Whh;
        float* hall = ws + HALL_OFF;
        unsigned* bar = (unsigned*)(ws + BAR_OFF);
        void* args[] = { (void*)&xih, (void*)&whh, (void*)&hall, (void*)&bar };
        hipLaunchCooperativeKernel((void*)k_lstm, dim3(NBLK), dim3(256), args, 0, stream);
    }

    if (use_mfma) {
        // (VV*HH + 768*HH)/8 octets = 2,097,152 -> 8192 blocks
        k_cvt<<<dim3(8192), 256, 0, stream>>>(Wread, ws + HALL_OFF + (size_t)SS * BB * HH,
                                              (unsigned short*)(ws + WBF_OFF),
                                              (unsigned short*)(ws + ABF_OFF));
    }

    k_q<<<dim3(TM), 256, 0, stream>>>(ws + HALL_OFF, Watt, ws + Q_OFF);

    k_att<<<dim3(TM, BB), 256, 0, stream>>>(ws + HALL_OFF, ws + Q_OFF, sent,
                                            src, tgt, ws + PPTR_OFF, ws + ASENT_OFF);

    if (use_mfma) {
        k_vocab_mfma<<<dim3(VV / 64), 256, 0, stream>>>(
            (const unsigned short*)(ws + ABF_OFF),
            (const unsigned short*)(ws + WBF_OFF),
            tgt, ws + SSUM_OFF, ws + LSTAR_OFF);
    } else {
        k_vocab_f32<<<dim3(63, 6), 256, 0, stream>>>(ws + HALL_OFF, Wread, tgt,
                                                     ws + SSUM_OFF, ws + LSTAR_OFF);
    }

    k_final<<<dim3(1), dim3(TM * BB), 0, stream>>>(ws + PPTR_OFF, ws + ASENT_OFF,
                                                   ws + SSUM_OFF, ws + LSTAR_OFF,
                                                   tgt, out);
}